// Round 13
// baseline (1058.858 us; speedup 1.0000x reference)
//
#include <hip/hip_runtime.h>
#include <hip/hip_bf16.h>

typedef __hip_bfloat16 bf16;
typedef __attribute__((ext_vector_type(8))) short short8;   // 8 bf16 = 4 VGPRs
typedef __attribute__((ext_vector_type(4))) short short4v;  // 4 bf16 = 8 B
typedef __attribute__((ext_vector_type(4))) float floatx4;  // MFMA C/D

#define SEQ 4096
#define DIM 1024
#define NH 16
#define HD 64

__device__ __forceinline__ short f2s(float f) { bf16 t = __float2bfloat16(f); return *(short*)&t; }

__device__ __forceinline__ float fexp2(float x) {
#if __has_builtin(__builtin_amdgcn_exp2f)
    return __builtin_amdgcn_exp2f(x);
#else
    return exp2f(x);
#endif
}

// async global->LDS, 16B per lane; LDS dest = wave-uniform base + lane*16
__device__ __forceinline__ void gload16(const void* g, void* l) {
    __builtin_amdgcn_global_load_lds(
        (const __attribute__((address_space(1))) void*)g,
        (__attribute__((address_space(3))) void*)l, 16, 0, 0);
}

__device__ __forceinline__ short8 cvt8(float4 a, float4 b) {
    short8 s;
    s[0] = f2s(a.x); s[1] = f2s(a.y); s[2] = f2s(a.z); s[3] = f2s(a.w);
    s[4] = f2s(b.x); s[5] = f2s(b.y); s[6] = f2s(b.z); s[7] = f2s(b.w);
    return s;
}

// ---------------------------------------------------------------------------
// Transpose+cast: W fp32 [K][N] -> Wt bf16 [N][K]. blockIdx.z selects weight.
// ---------------------------------------------------------------------------
__global__ __launch_bounds__(256) void transpose_cast_kernel(
    const float* __restrict__ W0, const float* __restrict__ W1,
    const float* __restrict__ W2, const float* __restrict__ W3,
    bf16* __restrict__ Wt_all)
{
    const float* W = blockIdx.z == 0 ? W0 : blockIdx.z == 1 ? W1
                   : blockIdx.z == 2 ? W2 : W3;
    bf16* Wt = Wt_all + (size_t)blockIdx.z * DIM * DIM;

    __shared__ float tile[32][33];
    const int n0 = blockIdx.x * 32, k0 = blockIdx.y * 32;
    const int tr = threadIdx.x >> 5;
    const int tc = threadIdx.x & 31;
#pragma unroll
    for (int i = 0; i < 32; i += 8)
        tile[tr + i][tc] = W[(size_t)(k0 + tr + i) * DIM + n0 + tc];
    __syncthreads();
#pragma unroll
    for (int i = 0; i < 32; i += 8)
        Wt[(size_t)(n0 + tr + i) * DIM + k0 + tc] = __float2bfloat16(tile[tc][tr + i]);
}

// ---------------------------------------------------------------------------
// Fused QKV GEMM, fp32-A path (round-10/11 proven): C_z = x(fp32) @ Wt_z^T.
// Q output (z==0) pre-scaled by (1/sqrt(HD)) * log2(e) — attention uses exp2.
// ---------------------------------------------------------------------------
#define QBM 128
#define QBN 128
#define QBK 64
#define QSCALE 0.1803368801111244f   // 0.125 * log2(e)

__global__ __launch_bounds__(256) void qkv_gemm_kernel(
    const float* __restrict__ A, const bf16* __restrict__ Wt,
    bf16* __restrict__ Qb, bf16* __restrict__ Kb, bf16* __restrict__ Vb)
{
    const int z = blockIdx.z;
    const bf16* Bt = Wt + (size_t)z * DIM * DIM;
    bf16* C = z == 0 ? Qb : (z == 1 ? Kb : Vb);
    const float osc = (z == 0) ? QSCALE : 1.0f;

    __shared__ alignas(16) float Af[QBM][QBK];   // 32 KB
    __shared__ alignas(16) short Bs[QBN][QBK];   // 16 KB

    const int tid  = threadIdx.x;
    const int wave = tid >> 6, lane = tid & 63;
    const int l15  = lane & 15, quad = lane >> 4;
    const int wm = (wave & 1) * 64;
    const int wn = (wave >> 1) * 64;
    const int bm = blockIdx.y * QBM;
    const int bn = blockIdx.x * QBN;

    const int arow = tid >> 4;
    const int agch = (tid & 15) ^ (arow & 15);
    const float* gA = A + (size_t)(bm + arow) * DIM + agch * 4;
    char* ldsA = (char*)&Af[0][0] + wave * 1024;

    const int brow = tid >> 3;
    const int bgch = (tid & 7) ^ (brow & 7);
    const bf16* gB = Bt + (size_t)(bn + brow) * DIM + bgch * 8;
    char* ldsB = (char*)&Bs[0][0] + wave * 1024;

    floatx4 acc[4][4] = {};

    for (int k0 = 0; k0 < DIM; k0 += QBK) {
        __syncthreads();
#pragma unroll
        for (int c = 0; c < 8; ++c)
            gload16(gA + (size_t)c * 16 * DIM + k0, ldsA + c * 4096);
#pragma unroll
        for (int c = 0; c < 4; ++c)
            gload16(gB + (size_t)c * 32 * DIM + k0, ldsB + c * 4096);
        __syncthreads();

#pragma unroll
        for (int c2 = 0; c2 < 2; ++c2) {
            const int g0 = c2 * 8 + quad * 2;
            const int cb = (c2 * 4 + quad) ^ (l15 & 7);
            short8 afr[4], bfr[4];
#pragma unroll
            for (int i = 0; i < 4; ++i) {
                const int ra = wm + i * 16 + l15;
                float4 f0 = *(const float4*)&Af[ra][(g0 ^ l15) * 4];
                float4 f1 = *(const float4*)&Af[ra][((g0 + 1) ^ l15) * 4];
                afr[i] = cvt8(f0, f1);
                bfr[i] = *(const short8*)&Bs[wn + i * 16 + l15][cb * 8];
            }
#pragma unroll
            for (int mi = 0; mi < 4; ++mi)
#pragma unroll
                for (int ni = 0; ni < 4; ++ni)
                    acc[mi][ni] = __builtin_amdgcn_mfma_f32_16x16x32_bf16(
                        afr[mi], bfr[ni], acc[mi][ni], 0, 0, 0);
        }
    }

#pragma unroll
    for (int mi = 0; mi < 4; ++mi)
#pragma unroll
        for (int r = 0; r < 4; ++r) {
            const int row = bm + wm + mi * 16 + quad * 4 + r;
#pragma unroll
            for (int ni = 0; ni < 4; ++ni) {
                const int col = bn + wn + ni * 16 + l15;
                C[(size_t)row * DIM + col] = __float2bfloat16(acc[mi][ni][r] * osc);
            }
        }
}

// ---------------------------------------------------------------------------
// Final GEMM (unchanged): out = ctx(bf16) @ Wo^T + bias. 128x64, 512 blocks.
// ---------------------------------------------------------------------------
__global__ __launch_bounds__(256) void out_gemm_kernel(
    const bf16* __restrict__ A, const bf16* __restrict__ Bt,
    const float* __restrict__ bias, float* __restrict__ C)
{
    __shared__ alignas(16) short Asl[128][64];
    __shared__ alignas(16) short Bsl[64][64];

    const int tid  = threadIdx.x;
    const int wave = tid >> 6, lane = tid & 63;
    const int l15  = lane & 15, quad = lane >> 4;
    const int wm = (wave & 1) * 64;
    const int wn = (wave >> 1) * 32;
    const int bm = blockIdx.y * 128;
    const int bn = blockIdx.x * 64;

    const int srow   = tid >> 3;
    const int gchunk = (tid & 7) ^ (srow & 7);
    const bf16* gA = A  + (size_t)(bm + srow) * DIM + gchunk * 8;
    const bf16* gB = Bt + (size_t)(bn + srow) * DIM + gchunk * 8;
    char* ldsA = (char*)&Asl[0][0] + wave * 1024;
    char* ldsB = (char*)&Bsl[0][0] + wave * 1024;

    floatx4 acc[4][2] = {};

    for (int k0 = 0; k0 < DIM; k0 += 64) {
        __syncthreads();
#pragma unroll
        for (int c = 0; c < 4; ++c)
            gload16(gA + (size_t)c * 32 * DIM + k0, ldsA + c * 4096);
#pragma unroll
        for (int c = 0; c < 2; ++c)
            gload16(gB + (size_t)c * 32 * DIM + k0, ldsB + c * 4096);
        __syncthreads();

#pragma unroll
        for (int c2 = 0; c2 < 2; ++c2) {
            const int cb = (c2 * 4 + quad) ^ (l15 & 7);
            short8 afr[4], bfr[2];
#pragma unroll
            for (int i = 0; i < 4; ++i)
                afr[i] = *(const short8*)&Asl[wm + i * 16 + l15][cb * 8];
#pragma unroll
            for (int i = 0; i < 2; ++i)
                bfr[i] = *(const short8*)&Bsl[wn + i * 16 + l15][cb * 8];
#pragma unroll
            for (int mi = 0; mi < 4; ++mi)
#pragma unroll
                for (int ni = 0; ni < 2; ++ni)
                    acc[mi][ni] = __builtin_amdgcn_mfma_f32_16x16x32_bf16(
                        afr[mi], bfr[ni], acc[mi][ni], 0, 0, 0);
        }
    }

#pragma unroll
    for (int mi = 0; mi < 4; ++mi)
#pragma unroll
        for (int r = 0; r < 4; ++r) {
            const int row = bm + wm + mi * 16 + quad * 4 + r;
#pragma unroll
            for (int ni = 0; ni < 2; ++ni) {
                const int col = bn + wn + ni * 16 + l15;
                C[(size_t)row * DIM + col] = acc[mi][ni][r] + bias[col];
            }
        }
}

// ---------------------------------------------------------------------------
// Flash attention v7 = v6 + PING-PONG REGISTER PREFETCH issued at the TOP of
// each iteration. __syncthreads drains vmcnt(0) (compiler semantics), so
// loads issued just before the barrier (v6) expose full L2/HBM latency every
// tile. Now: at top of iter kt, regs[p] already holds tile kt+1 and we ISSUE
// loads for tile kt+2 into regs[p^1]; staging ds_writes from regs[p] happen
// at the end. By barrier time the loads have a full tile of compute (~2000
// cyc) in flight -> drain ~free. +16 VGPRs, no occupancy change.
// Also: P = exp2(S) with log2(e) folded into the Q-projection scale.
// Unpadded XOR-swizzled LDS, Qs/Ps union, S^T b64 P-packing, one barrier
// per tile, balanced pairing, m=0 fixed shift, ones-MFMA row-sum.
// ---------------------------------------------------------------------------
#define QT 128
#define KT 64

__global__ __launch_bounds__(256) void flash_attn_kernel(
    const bf16* __restrict__ Q, const bf16* __restrict__ K,
    const bf16* __restrict__ V, bf16* ctx)
{
    const int lin  = blockIdx.y * 32 + blockIdx.x;
    const int half = lin >> 8, idx = lin & 255;
    const int qj   = half ? (idx & 31) : 31 - (idx & 31);
    const int h    = (idx >> 5) + 8 * half;
    const int q0   = qj * QT;
    const int nkt  = 2 * qj + 2;

    const int tid  = threadIdx.x;
    const int wave = tid >> 6;
    const int lane = tid & 63;
    const int l15  = lane & 15;
    const int quad = lane >> 4;
    const int le   = l15 & 7;

    __shared__ alignas(16) short QP[128 * 64];      // 16 KB: Qs, then Ps
    __shared__ alignas(16) short Ks[2][64 * 64];    // 16 KB [buf][key][dim]
    __shared__ alignas(16) short Vt[2][64 * 64];    // 16 KB [buf][dim][key]

    // ---- stage Q (swizzled chunks) ----
    {
        const int r = tid >> 1, e = r & 7;
        const short8* src = (const short8*)(Q + (size_t)(q0 + r) * DIM + h * HD + (tid & 1) * 32);
#pragma unroll
        for (int i = 0; i < 4; ++i) {
            const int c = (tid & 1) * 4 + i;
            *(short8*)&QP[r * 64 + ((c ^ e) * 8)] = src[i];
        }
    }

    const int kr = tid >> 2, ke = kr & 7, kc0 = (tid & 3) * 2;   // K map
    const int vw = tid & 31, vd = (tid >> 5) * 8, vr = vw * 2;   // V map

    // ---- tile 0 -> buf0 directly (temp regs) ----
    {
        const short8* kp  = (const short8*)(K + (size_t)kr * DIM + h * HD + kc0 * 8);
        short8 k0r = kp[0], k1r = kp[1];
        const short8* vp0 = (const short8*)(V + (size_t)vr * DIM + h * HD + vd);
        const short8* vp1 = (const short8*)(V + (size_t)(vr + 1) * DIM + h * HD + vd);
        short8 v0r = vp0[0], v1r = vp1[0];
        *(short8*)&Ks[0][kr * 64 + ((kc0 ^ ke) * 8)]       = k0r;
        *(short8*)&Ks[0][kr * 64 + (((kc0 + 1) ^ ke) * 8)] = k1r;
#pragma unroll
        for (int i = 0; i < 8; ++i) {
            unsigned int pv = (unsigned int)(unsigned short)v0r[i]
                            | ((unsigned int)(unsigned short)v1r[i] << 16);
            const int row = vd + i;
            *(unsigned int*)&Vt[0][row * 64 + (((vw >> 2) ^ (row & 7)) * 8) + (vw & 3) * 2] = pv;
        }
    }

    // ---- ping-pong prefetch regs; regs[0] <- tile 1 (nkt >= 2 always) ----
    short8 kreg[2][2], vreg[2][2];
    {
        const size_t nb = (size_t)KT;
        const short8* kp  = (const short8*)(K + (nb + kr) * DIM + h * HD + kc0 * 8);
        kreg[0][0] = kp[0]; kreg[0][1] = kp[1];
        const short8* vp0 = (const short8*)(V + (nb + vr) * DIM + h * HD + vd);
        const short8* vp1 = (const short8*)(V + (nb + vr + 1) * DIM + h * HD + vd);
        vreg[0][0] = vp0[0]; vreg[0][1] = vp1[0];
    }

    __syncthreads();   // Qs + buf0 visible

    short8 qfrag[2][2];
#pragma unroll
    for (int s = 0; s < 2; ++s)
#pragma unroll
        for (int c = 0; c < 2; ++c)
            qfrag[s][c] = *(const short8*)&QP[(wave * 32 + s * 16 + l15) * 64
                                              + (((c * 4 + quad) ^ le) * 8)];

    short8 onesf;
#pragma unroll
    for (int i = 0; i < 8; ++i) onesf[i] = (short)0x3F80;   // bf16 1.0

    floatx4 o_acc[2][4] = {};
    floatx4 lacc[2] = {};
    const int prow = wave * 32 + l15;

    for (int kt = 0; kt < nkt; ++kt) {
        const int b = kt & 1;   // LDS buf for this tile; also reg set holding kt+1

        // ---- ISSUE loads for tile kt+2 into regs[b^1] (drained ~1 tile later) ----
        if (kt + 2 < nkt) {
            const size_t nb = (size_t)(kt + 2) * KT;
            const short8* kp  = (const short8*)(K + (nb + kr) * DIM + h * HD + kc0 * 8);
            kreg[b ^ 1][0] = kp[0]; kreg[b ^ 1][1] = kp[1];
            const short8* vp0 = (const short8*)(V + (nb + vr) * DIM + h * HD + vd);
            const short8* vp1 = (const short8*)(V + (nb + vr + 1) * DIM + h * HD + vd);
            vreg[b ^ 1][0] = vp0[0]; vreg[b ^ 1][1] = vp1[0];
        }

        // ---- S^T = K . Q^T ----
        floatx4 sT[2][4] = {};
#pragma unroll
        for (int n = 0; n < 4; ++n)
#pragma unroll
            for (int c = 0; c < 2; ++c) {
                short8 kf = *(const short8*)&Ks[b][(n * 16 + l15) * 64
                                                   + (((c * 4 + quad) ^ le) * 8)];
#pragma unroll
                for (int s = 0; s < 2; ++s)
                    sT[s][n] = __builtin_amdgcn_mfma_f32_16x16x32_bf16(
                        kf, qfrag[s][c], sT[s][n], 0, 0, 0);
            }

        // ---- p = exp2(s) (+ mask near diag), swizzled b64 writes into QP ----
        const int kbase = kt * KT;
        if (kt >= nkt - 2) {
#pragma unroll
            for (int s = 0; s < 2; ++s) {
                const int qrow = q0 + wave * 32 + s * 16 + l15;
#pragma unroll
                for (int n = 0; n < 4; ++n) {
                    const int key0 = kbase + n * 16 + quad * 4;
                    short4v pk;
#pragma unroll
                    for (int r = 0; r < 4; ++r)
                        pk[r] = f2s((key0 + r <= qrow) ? fexp2(sT[s][n][r]) : 0.f);
                    *(short4v*)&QP[(prow + s * 16) * 64
                                   + (((n * 2 + (quad >> 1)) ^ le) * 8) + (quad & 1) * 4] = pk;
                }
            }
        } else {
#pragma unroll
            for (int s = 0; s < 2; ++s)
#pragma unroll
                for (int n = 0; n < 4; ++n) {
                    short4v pk;
#pragma unroll
                    for (int r = 0; r < 4; ++r)
                        pk[r] = f2s(fexp2(sT[s][n][r]));
                    *(short4v*)&QP[(prow + s * 16) * 64
                                   + (((n * 2 + (quad >> 1)) ^ le) * 8) + (quad & 1) * 4] = pk;
                }
        }

        // ---- O += P V ; l += P . 1 (wave-local; lgkmcnt ordering) ----
        short8 pfrag[2][2];
#pragma unroll
        for (int s = 0; s < 2; ++s)
#pragma unroll
            for (int c = 0; c < 2; ++c)
                pfrag[s][c] = *(const short8*)&QP[(prow + s * 16) * 64
                                                  + (((c * 4 + quad) ^ le) * 8)];
#pragma unroll
        for (int n = 0; n < 4; ++n)
#pragma unroll
            for (int c = 0; c < 2; ++c) {
                short8 vf = *(const short8*)&Vt[b][(n * 16 + l15) * 64
                                                   + (((c * 4 + quad) ^ le) * 8)];
#pragma unroll
                for (int s = 0; s < 2; ++s)
                    o_acc[s][n] = __builtin_amdgcn_mfma_f32_16x16x32_bf16(
                        pfrag[s][c], vf, o_acc[s][n], 0, 0, 0);
            }
#pragma unroll
        for (int s = 0; s < 2; ++s) {
            lacc[s] = __builtin_amdgcn_mfma_f32_16x16x32_bf16(pfrag[s][0], onesf, lacc[s], 0, 0, 0);
            lacc[s] = __builtin_amdgcn_mfma_f32_16x16x32_bf16(pfrag[s][1], onesf, lacc[s], 0, 0, 0);
        }

        // ---- stage tile kt+1 from regs[b] into buf[b^1] ----
        if (kt + 1 < nkt) {
            *(short8*)&Ks[b ^ 1][kr * 64 + ((kc0 ^ ke) * 8)]       = kreg[b][0];
            *(short8*)&Ks[b ^ 1][kr * 64 + (((kc0 + 1) ^ ke) * 8)] = kreg[b][1];
#pragma unroll
            for (int i = 0; i < 8; ++i) {
                unsigned int pv = (unsigned int)(unsigned short)vreg[b][0][i]
                                | ((unsigned int)(unsigned short)vreg[b][1][i] << 16);
                const int row = vd + i;
                *(unsigned int*)&Vt[b ^ 1][row * 64 + (((vw >> 2) ^ (row & 7)) * 8) + (vw & 3) * 2] = pv;
            }
        }
        __syncthreads();   // buf[b^1] visible; reads of buf[b] complete
    }

    // ---- epilogue: O / l -> ctx ----
#pragma unroll
    for (int s = 0; s < 2; ++s)
#pragma unroll
        for (int r = 0; r < 4; ++r) {
            const float inv = 1.0f / lacc[s][r];
            const int row = q0 + wave * 32 + s * 16 + quad * 4 + r;
#pragma unroll
            for (int n = 0; n < 4; ++n)
                ctx[(size_t)row * DIM + h * HD + n * 16 + l15] =
                    __float2bfloat16(o_acc[s][n][r] * inv);
        }
}

// ---------------------------------------------------------------------------
// Memory plan (16 MB ws):
//   ws[0 : 8MB]  = Wt_all (4 x bf16 [N][K]);  ws[8 : 16MB] = Q -> ctx
//   d_out[0:8MB] (bf16) = V scratch; d_out[8:16MB] = K scratch
// x read directly (fp32) by the fused QKV GEMM.
// ---------------------------------------------------------------------------
extern "C" void kernel_launch(void* const* d_in, const int* in_sizes, int n_in,
                              void* d_out, int out_size, void* d_ws, size_t ws_size,
                              hipStream_t stream)
{
    const float* x  = (const float*)d_in[0];
    const float* Wq = (const float*)d_in[1];
    const float* Wk = (const float*)d_in[2];
    const float* Wv = (const float*)d_in[3];
    const float* Wo = (const float*)d_in[4];
    const float* bo = (const float*)d_in[5];
    float* out = (float*)d_out;

    bf16* Wt_all = (bf16*)d_ws;
    bf16* Qb     = Wt_all + (size_t)4 * DIM * DIM;
    bf16* V      = (bf16*)d_out;
    bf16* Kb     = V + (size_t)SEQ * DIM;
    bf16* ctx    = Qb;
    const bf16* Wot = Wt_all + (size_t)3 * DIM * DIM;

    transpose_cast_kernel<<<dim3(32, 32, 4), 256, 0, stream>>>(Wq, Wk, Wv, Wo, Wt_all);

    qkv_gemm_kernel<<<dim3(DIM / QBN, SEQ / QBM, 3), 256, 0, stream>>>(
        x, Wt_all, Qb, Kb, V);

    flash_attn_kernel<<<dim3(32, NH), 256, 0, stream>>>(Qb, Kb, V, ctx);

    out_gemm_kernel<<<dim3(DIM / 64, SEQ / 128), 256, 0, stream>>>(
        ctx, Wot, bo, out);
}

// Round 14
// 200.399 us; speedup vs baseline: 5.2837x; 5.2837x over previous
//
#include <hip/hip_runtime.h>
#include <hip/hip_bf16.h>

typedef __hip_bfloat16 bf16;
typedef __attribute__((ext_vector_type(8))) short short8;   // 8 bf16 = 4 VGPRs
typedef __attribute__((ext_vector_type(4))) short short4v;  // 4 bf16 = 8 B
typedef __attribute__((ext_vector_type(4))) float floatx4;  // MFMA C/D

#define SEQ 4096
#define DIM 1024
#define NH 16
#define HD 64

__device__ __forceinline__ short f2s(float f) { bf16 t = __float2bfloat16(f); return *(short*)&t; }

__device__ __forceinline__ float fexp2(float x) {
#if __has_builtin(__builtin_amdgcn_exp2f)
    return __builtin_amdgcn_exp2f(x);
#else
    return exp2f(x);
#endif
}

// async global->LDS, 16B per lane; LDS dest = wave-uniform base + lane*16
__device__ __forceinline__ void gload16(const void* g, void* l) {
    __builtin_amdgcn_global_load_lds(
        (const __attribute__((address_space(1))) void*)g,
        (__attribute__((address_space(3))) void*)l, 16, 0, 0);
}

__device__ __forceinline__ short8 cvt8(float4 a, float4 b) {
    short8 s;
    s[0] = f2s(a.x); s[1] = f2s(a.y); s[2] = f2s(a.z); s[3] = f2s(a.w);
    s[4] = f2s(b.x); s[5] = f2s(b.y); s[6] = f2s(b.z); s[7] = f2s(b.w);
    return s;
}

// ---------------------------------------------------------------------------
// Transpose+cast: W fp32 [K][N] -> Wt bf16 [N][K]. blockIdx.z selects weight.
// ---------------------------------------------------------------------------
__global__ __launch_bounds__(256) void transpose_cast_kernel(
    const float* __restrict__ W0, const float* __restrict__ W1,
    const float* __restrict__ W2, const float* __restrict__ W3,
    bf16* __restrict__ Wt_all)
{
    const float* W = blockIdx.z == 0 ? W0 : blockIdx.z == 1 ? W1
                   : blockIdx.z == 2 ? W2 : W3;
    bf16* Wt = Wt_all + (size_t)blockIdx.z * DIM * DIM;

    __shared__ float tile[32][33];
    const int n0 = blockIdx.x * 32, k0 = blockIdx.y * 32;
    const int tr = threadIdx.x >> 5;
    const int tc = threadIdx.x & 31;
#pragma unroll
    for (int i = 0; i < 32; i += 8)
        tile[tr + i][tc] = W[(size_t)(k0 + tr + i) * DIM + n0 + tc];
    __syncthreads();
#pragma unroll
    for (int i = 0; i < 32; i += 8)
        Wt[(size_t)(n0 + tr + i) * DIM + k0 + tc] = __float2bfloat16(tile[tc][tr + i]);
}

// ---------------------------------------------------------------------------
// Fused QKV GEMM, fp32-A path (round-10/11 proven): C_z = x(fp32) @ Wt_z^T.
// Q output (z==0) pre-scaled by (1/sqrt(HD)) * log2(e) — attention uses exp2.
// ---------------------------------------------------------------------------
#define QBM 128
#define QBN 128
#define QBK 64
#define QSCALE 0.1803368801111244f   // 0.125 * log2(e)

__global__ __launch_bounds__(256) void qkv_gemm_kernel(
    const float* __restrict__ A, const bf16* __restrict__ Wt,
    bf16* __restrict__ Qb, bf16* __restrict__ Kb, bf16* __restrict__ Vb)
{
    const int z = blockIdx.z;
    const bf16* Bt = Wt + (size_t)z * DIM * DIM;
    bf16* C = z == 0 ? Qb : (z == 1 ? Kb : Vb);
    const float osc = (z == 0) ? QSCALE : 1.0f;

    __shared__ alignas(16) float Af[QBM][QBK];   // 32 KB
    __shared__ alignas(16) short Bs[QBN][QBK];   // 16 KB

    const int tid  = threadIdx.x;
    const int wave = tid >> 6, lane = tid & 63;
    const int l15  = lane & 15, quad = lane >> 4;
    const int wm = (wave & 1) * 64;
    const int wn = (wave >> 1) * 64;
    const int bm = blockIdx.y * QBM;
    const int bn = blockIdx.x * QBN;

    const int arow = tid >> 4;
    const int agch = (tid & 15) ^ (arow & 15);
    const float* gA = A + (size_t)(bm + arow) * DIM + agch * 4;
    char* ldsA = (char*)&Af[0][0] + wave * 1024;

    const int brow = tid >> 3;
    const int bgch = (tid & 7) ^ (brow & 7);
    const bf16* gB = Bt + (size_t)(bn + brow) * DIM + bgch * 8;
    char* ldsB = (char*)&Bs[0][0] + wave * 1024;

    floatx4 acc[4][4] = {};

    for (int k0 = 0; k0 < DIM; k0 += QBK) {
        __syncthreads();
#pragma unroll
        for (int c = 0; c < 8; ++c)
            gload16(gA + (size_t)c * 16 * DIM + k0, ldsA + c * 4096);
#pragma unroll
        for (int c = 0; c < 4; ++c)
            gload16(gB + (size_t)c * 32 * DIM + k0, ldsB + c * 4096);
        __syncthreads();

#pragma unroll
        for (int c2 = 0; c2 < 2; ++c2) {
            const int g0 = c2 * 8 + quad * 2;
            const int cb = (c2 * 4 + quad) ^ (l15 & 7);
            short8 afr[4], bfr[4];
#pragma unroll
            for (int i = 0; i < 4; ++i) {
                const int ra = wm + i * 16 + l15;
                float4 f0 = *(const float4*)&Af[ra][(g0 ^ l15) * 4];
                float4 f1 = *(const float4*)&Af[ra][((g0 + 1) ^ l15) * 4];
                afr[i] = cvt8(f0, f1);
                bfr[i] = *(const short8*)&Bs[wn + i * 16 + l15][cb * 8];
            }
#pragma unroll
            for (int mi = 0; mi < 4; ++mi)
#pragma unroll
                for (int ni = 0; ni < 4; ++ni)
                    acc[mi][ni] = __builtin_amdgcn_mfma_f32_16x16x32_bf16(
                        afr[mi], bfr[ni], acc[mi][ni], 0, 0, 0);
        }
    }

#pragma unroll
    for (int mi = 0; mi < 4; ++mi)
#pragma unroll
        for (int r = 0; r < 4; ++r) {
            const int row = bm + wm + mi * 16 + quad * 4 + r;
#pragma unroll
            for (int ni = 0; ni < 4; ++ni) {
                const int col = bn + wn + ni * 16 + l15;
                C[(size_t)row * DIM + col] = __float2bfloat16(acc[mi][ni][r] * osc);
            }
        }
}

// ---------------------------------------------------------------------------
// Final GEMM (unchanged): out = ctx(bf16) @ Wo^T + bias. 128x64, 512 blocks.
// ---------------------------------------------------------------------------
__global__ __launch_bounds__(256) void out_gemm_kernel(
    const bf16* __restrict__ A, const bf16* __restrict__ Bt,
    const float* __restrict__ bias, float* __restrict__ C)
{
    __shared__ alignas(16) short Asl[128][64];
    __shared__ alignas(16) short Bsl[64][64];

    const int tid  = threadIdx.x;
    const int wave = tid >> 6, lane = tid & 63;
    const int l15  = lane & 15, quad = lane >> 4;
    const int wm = (wave & 1) * 64;
    const int wn = (wave >> 1) * 32;
    const int bm = blockIdx.y * 128;
    const int bn = blockIdx.x * 64;

    const int srow   = tid >> 3;
    const int gchunk = (tid & 7) ^ (srow & 7);
    const bf16* gA = A  + (size_t)(bm + srow) * DIM + gchunk * 8;
    const bf16* gB = Bt + (size_t)(bn + srow) * DIM + gchunk * 8;
    char* ldsA = (char*)&Asl[0][0] + wave * 1024;
    char* ldsB = (char*)&Bsl[0][0] + wave * 1024;

    floatx4 acc[4][2] = {};

    for (int k0 = 0; k0 < DIM; k0 += 64) {
        __syncthreads();
#pragma unroll
        for (int c = 0; c < 4; ++c)
            gload16(gA + (size_t)c * 32 * DIM + k0, ldsA + c * 4096);
#pragma unroll
        for (int c = 0; c < 2; ++c)
            gload16(gB + (size_t)c * 32 * DIM + k0, ldsB + c * 4096);
        __syncthreads();

#pragma unroll
        for (int c2 = 0; c2 < 2; ++c2) {
            const int cb = (c2 * 4 + quad) ^ (l15 & 7);
            short8 afr[4], bfr[2];
#pragma unroll
            for (int i = 0; i < 4; ++i)
                afr[i] = *(const short8*)&Asl[wm + i * 16 + l15][cb * 8];
#pragma unroll
            for (int i = 0; i < 2; ++i)
                bfr[i] = *(const short8*)&Bsl[wn + i * 16 + l15][cb * 8];
#pragma unroll
            for (int mi = 0; mi < 4; ++mi)
#pragma unroll
                for (int ni = 0; ni < 2; ++ni)
                    acc[mi][ni] = __builtin_amdgcn_mfma_f32_16x16x32_bf16(
                        afr[mi], bfr[ni], acc[mi][ni], 0, 0, 0);
        }
    }

#pragma unroll
    for (int mi = 0; mi < 4; ++mi)
#pragma unroll
        for (int r = 0; r < 4; ++r) {
            const int row = bm + wm + mi * 16 + quad * 4 + r;
#pragma unroll
            for (int ni = 0; ni < 2; ++ni) {
                const int col = bn + wn + ni * 16 + l15;
                C[(size_t)row * DIM + col] = acc[mi][ni][r] + bias[col];
            }
        }
}

// ---------------------------------------------------------------------------
// Flash attention v8 = v7's ping-pong prefetch with COMPILE-TIME buffer
// indices. Round 13's regs[kt&1] dynamic indexing forced the compiler to
// spill / cndmask-expand the prefetch arrays (MfmaUtil 1.7%, 13x slower).
// nkt is always EVEN, so the K-loop unrolls by 2: after #pragma unroll,
// b==u is a constant and kreg[u]/Ks[u]/Vt[u] resolve statically.
// Schedule per sub-iter u (tile kt=kt2+u): issue global loads for kt+2 into
// regs[u^1] at the TOP (a full tile of compute before the barrier drain),
// compute from buf[u], stage regs[u] (tile kt+1) into buf[u^1] at the end.
// Unpadded XOR-swizzled LDS, Qs/Ps union, S^T b64 P-packing, one barrier
// per tile, balanced pairing, m=0, ones-MFMA row-sum, P=exp2(S) with
// log2(e) folded into the Q projection.
// ---------------------------------------------------------------------------
#define QT 128
#define KT 64

__global__ __launch_bounds__(256) void flash_attn_kernel(
    const bf16* __restrict__ Q, const bf16* __restrict__ K,
    const bf16* __restrict__ V, bf16* ctx)
{
    const int lin  = blockIdx.y * 32 + blockIdx.x;
    const int half = lin >> 8, idx = lin & 255;
    const int qj   = half ? (idx & 31) : 31 - (idx & 31);
    const int h    = (idx >> 5) + 8 * half;
    const int q0   = qj * QT;
    const int nkt  = 2 * qj + 2;   // always even

    const int tid  = threadIdx.x;
    const int wave = tid >> 6;
    const int lane = tid & 63;
    const int l15  = lane & 15;
    const int quad = lane >> 4;
    const int le   = l15 & 7;

    __shared__ alignas(16) short QP[128 * 64];      // 16 KB: Qs, then Ps
    __shared__ alignas(16) short Ks[2][64 * 64];    // 16 KB [buf][key][dim]
    __shared__ alignas(16) short Vt[2][64 * 64];    // 16 KB [buf][dim][key]

    // ---- stage Q (swizzled chunks) ----
    {
        const int r = tid >> 1, e = r & 7;
        const short8* src = (const short8*)(Q + (size_t)(q0 + r) * DIM + h * HD + (tid & 1) * 32);
#pragma unroll
        for (int i = 0; i < 4; ++i) {
            const int c = (tid & 1) * 4 + i;
            *(short8*)&QP[r * 64 + ((c ^ e) * 8)] = src[i];
        }
    }

    const int kr = tid >> 2, ke = kr & 7, kc0 = (tid & 3) * 2;   // K map
    const int vw = tid & 31, vd = (tid >> 5) * 8, vr = vw * 2;   // V map

    // ---- tile 0 -> buf0 directly (temp regs) ----
    {
        const short8* kp  = (const short8*)(K + (size_t)kr * DIM + h * HD + kc0 * 8);
        short8 k0r = kp[0], k1r = kp[1];
        const short8* vp0 = (const short8*)(V + (size_t)vr * DIM + h * HD + vd);
        const short8* vp1 = (const short8*)(V + (size_t)(vr + 1) * DIM + h * HD + vd);
        short8 v0r = vp0[0], v1r = vp1[0];
        *(short8*)&Ks[0][kr * 64 + ((kc0 ^ ke) * 8)]       = k0r;
        *(short8*)&Ks[0][kr * 64 + (((kc0 + 1) ^ ke) * 8)] = k1r;
#pragma unroll
        for (int i = 0; i < 8; ++i) {
            unsigned int pv = (unsigned int)(unsigned short)v0r[i]
                            | ((unsigned int)(unsigned short)v1r[i] << 16);
            const int row = vd + i;
            *(unsigned int*)&Vt[0][row * 64 + (((vw >> 2) ^ (row & 7)) * 8) + (vw & 3) * 2] = pv;
        }
    }

    // ---- ping-pong prefetch regs; regs[0] <- tile 1 (nkt >= 2 always) ----
    short8 kreg[2][2], vreg[2][2];
    {
        const size_t nb = (size_t)KT;
        const short8* kp  = (const short8*)(K + (nb + kr) * DIM + h * HD + kc0 * 8);
        kreg[0][0] = kp[0]; kreg[0][1] = kp[1];
        const short8* vp0 = (const short8*)(V + (nb + vr) * DIM + h * HD + vd);
        const short8* vp1 = (const short8*)(V + (nb + vr + 1) * DIM + h * HD + vd);
        vreg[0][0] = vp0[0]; vreg[0][1] = vp1[0];
    }

    __syncthreads();   // Qs + buf0 visible

    short8 qfrag[2][2];
#pragma unroll
    for (int s = 0; s < 2; ++s)
#pragma unroll
        for (int c = 0; c < 2; ++c)
            qfrag[s][c] = *(const short8*)&QP[(wave * 32 + s * 16 + l15) * 64
                                              + (((c * 4 + quad) ^ le) * 8)];

    short8 onesf;
#pragma unroll
    for (int i = 0; i < 8; ++i) onesf[i] = (short)0x3F80;   // bf16 1.0

    floatx4 o_acc[2][4] = {};
    floatx4 lacc[2] = {};
    const int prow = wave * 32 + l15;

    for (int kt2 = 0; kt2 < nkt; kt2 += 2) {
#pragma unroll
        for (int u = 0; u < 2; ++u) {          // u == buffer index, compile-time
            const int kt = kt2 + u;

            // ---- ISSUE loads for tile kt+2 into regs[u^1] ----
            if (kt + 2 < nkt) {
                const size_t nb = (size_t)(kt + 2) * KT;
                const short8* kp  = (const short8*)(K + (nb + kr) * DIM + h * HD + kc0 * 8);
                kreg[u ^ 1][0] = kp[0]; kreg[u ^ 1][1] = kp[1];
                const short8* vp0 = (const short8*)(V + (nb + vr) * DIM + h * HD + vd);
                const short8* vp1 = (const short8*)(V + (nb + vr + 1) * DIM + h * HD + vd);
                vreg[u ^ 1][0] = vp0[0]; vreg[u ^ 1][1] = vp1[0];
            }

            // ---- S^T = K . Q^T ----
            floatx4 sT[2][4] = {};
#pragma unroll
            for (int n = 0; n < 4; ++n)
#pragma unroll
                for (int c = 0; c < 2; ++c) {
                    short8 kf = *(const short8*)&Ks[u][(n * 16 + l15) * 64
                                                       + (((c * 4 + quad) ^ le) * 8)];
#pragma unroll
                    for (int s = 0; s < 2; ++s)
                        sT[s][n] = __builtin_amdgcn_mfma_f32_16x16x32_bf16(
                            kf, qfrag[s][c], sT[s][n], 0, 0, 0);
                }

            // ---- p = exp2(s) (+ mask near diag), swizzled b64 writes ----
            const int kbase = kt * KT;
            if (kt >= nkt - 2) {
#pragma unroll
                for (int s = 0; s < 2; ++s) {
                    const int qrow = q0 + wave * 32 + s * 16 + l15;
#pragma unroll
                    for (int n = 0; n < 4; ++n) {
                        const int key0 = kbase + n * 16 + quad * 4;
                        short4v pk;
#pragma unroll
                        for (int r = 0; r < 4; ++r)
                            pk[r] = f2s((key0 + r <= qrow) ? fexp2(sT[s][n][r]) : 0.f);
                        *(short4v*)&QP[(prow + s * 16) * 64
                                       + (((n * 2 + (quad >> 1)) ^ le) * 8) + (quad & 1) * 4] = pk;
                    }
                }
            } else {
#pragma unroll
                for (int s = 0; s < 2; ++s)
#pragma unroll
                    for (int n = 0; n < 4; ++n) {
                        short4v pk;
#pragma unroll
                        for (int r = 0; r < 4; ++r)
                            pk[r] = f2s(fexp2(sT[s][n][r]));
                        *(short4v*)&QP[(prow + s * 16) * 64
                                       + (((n * 2 + (quad >> 1)) ^ le) * 8) + (quad & 1) * 4] = pk;
                    }
            }

            // ---- O += P V ; l += P . 1 (wave-local; lgkmcnt ordering) ----
            short8 pfrag[2][2];
#pragma unroll
            for (int s = 0; s < 2; ++s)
#pragma unroll
                for (int c = 0; c < 2; ++c)
                    pfrag[s][c] = *(const short8*)&QP[(prow + s * 16) * 64
                                                      + (((c * 4 + quad) ^ le) * 8)];
#pragma unroll
            for (int n = 0; n < 4; ++n)
#pragma unroll
                for (int c = 0; c < 2; ++c) {
                    short8 vf = *(const short8*)&Vt[u][(n * 16 + l15) * 64
                                                       + (((c * 4 + quad) ^ le) * 8)];
#pragma unroll
                    for (int s = 0; s < 2; ++s)
                        o_acc[s][n] = __builtin_amdgcn_mfma_f32_16x16x32_bf16(
                            pfrag[s][c], vf, o_acc[s][n], 0, 0, 0);
                }
#pragma unroll
            for (int s = 0; s < 2; ++s) {
                lacc[s] = __builtin_amdgcn_mfma_f32_16x16x32_bf16(pfrag[s][0], onesf, lacc[s], 0, 0, 0);
                lacc[s] = __builtin_amdgcn_mfma_f32_16x16x32_bf16(pfrag[s][1], onesf, lacc[s], 0, 0, 0);
            }

            // ---- stage tile kt+1 from regs[u] into buf[u^1] ----
            if (kt + 1 < nkt) {
                *(short8*)&Ks[u ^ 1][kr * 64 + ((kc0 ^ ke) * 8)]       = kreg[u][0];
                *(short8*)&Ks[u ^ 1][kr * 64 + (((kc0 + 1) ^ ke) * 8)] = kreg[u][1];
#pragma unroll
                for (int i = 0; i < 8; ++i) {
                    unsigned int pv = (unsigned int)(unsigned short)vreg[u][0][i]
                                    | ((unsigned int)(unsigned short)vreg[u][1][i] << 16);
                    const int row = vd + i;
                    *(unsigned int*)&Vt[u ^ 1][row * 64 + (((vw >> 2) ^ (row & 7)) * 8) + (vw & 3) * 2] = pv;
                }
            }
            __syncthreads();   // buf[u^1] visible; reads of buf[u] complete
        }
    }

    // ---- epilogue: O / l -> ctx ----
#pragma unroll
    for (int s = 0; s < 2; ++s)
#pragma unroll
        for (int r = 0; r < 4; ++r) {
            const float inv = 1.0f / lacc[s][r];
            const int row = q0 + wave * 32 + s * 16 + quad * 4 + r;
#pragma unroll
            for (int n = 0; n < 4; ++n)
                ctx[(size_t)row * DIM + h * HD + n * 16 + l15] =
                    __float2bfloat16(o_acc[s][n][r] * inv);
        }
}

// ---------------------------------------------------------------------------
// Memory plan (16 MB ws):
//   ws[0 : 8MB]  = Wt_all (4 x bf16 [N][K]);  ws[8 : 16MB] = Q -> ctx
//   d_out[0:8MB] (bf16) = V scratch; d_out[8:16MB] = K scratch
// x read directly (fp32) by the fused QKV GEMM.
// ---------------------------------------------------------------------------
extern "C" void kernel_launch(void* const* d_in, const int* in_sizes, int n_in,
                              void* d_out, int out_size, void* d_ws, size_t ws_size,
                              hipStream_t stream)
{
    const float* x  = (const float*)d_in[0];
    const float* Wq = (const float*)d_in[1];
    const float* Wk = (const float*)d_in[2];
    const float* Wv = (const float*)d_in[3];
    const float* Wo = (const float*)d_in[4];
    const float* bo = (const float*)d_in[5];
    float* out = (float*)d_out;

    bf16* Wt_all = (bf16*)d_ws;
    bf16* Qb     = Wt_all + (size_t)4 * DIM * DIM;
    bf16* V      = (bf16*)d_out;
    bf16* Kb     = V + (size_t)SEQ * DIM;
    bf16* ctx    = Qb;
    const bf16* Wot = Wt_all + (size_t)3 * DIM * DIM;

    transpose_cast_kernel<<<dim3(32, 32, 4), 256, 0, stream>>>(Wq, Wk, Wv, Wo, Wt_all);

    qkv_gemm_kernel<<<dim3(DIM / QBN, SEQ / QBM, 3), 256, 0, stream>>>(
        x, Wt_all, Qb, Kb, V);

    flash_attn_kernel<<<dim3(32, NH), 256, 0, stream>>>(Qb, Kb, V, ctx);

    out_gemm_kernel<<<dim3(DIM / 64, SEQ / 128), 256, 0, stream>>>(
        ctx, Wot, bo, out);
}